// Round 6
// baseline (4711.266 us; speedup 1.0000x reference)
//
#include <hip/hip_runtime.h>
#include <cmath>

// Problem constants: B=256, T=256, D=128, E=32, F1=F2=512
#define B_   256
#define T_   256
#define D_   128
#define E_   32
#define F_   512
#define CB   16             // blocks per cluster
#define RC   16             // rows per cluster
#define NCL  16             // clusters
#define WPB  4              // waves per block
#define ALPHA_F 0.1f
#define SCALE_F 0.31622776601683794f   // sqrt(0.1)
#define WS_SYNC_BYTES 4096

typedef float f32x4 __attribute__((ext_vector_type(4)));
typedef short s16x8 __attribute__((ext_vector_type(8)));
#define MFMA __builtin_amdgcn_mfma_f32_16x16x32_bf16

// ---- bf16 helpers (RNE) ----
__device__ __forceinline__ unsigned short f2bf(float f) {
    unsigned u = __float_as_uint(f);
    return (unsigned short)((u + 0x7FFFu + ((u >> 16) & 1u)) >> 16);
}
__device__ __forceinline__ unsigned pack2(float lo, float hi) {
    return (unsigned)f2bf(lo) | ((unsigned)f2bf(hi) << 16);
}

// ---- coherent-point primitives (sc0 sc1) ----
__device__ __forceinline__ void st_coh_u32(unsigned* p, unsigned v) {
    __hip_atomic_store(p, v, __ATOMIC_RELAXED, __HIP_MEMORY_SCOPE_AGENT);
}
__device__ __forceinline__ unsigned long long ld_coh_u64(const unsigned long long* p) {
    return __hip_atomic_load(p, __ATOMIC_RELAXED, __HIP_MEMORY_SCOPE_AGENT);
}

// A/B-fragment (8 bf16) from a frag buffer at coherent point.
// Layout: u32 index (S*64 + lane)*4 + piece.
__device__ __forceinline__ s16x8 ld_frag(const unsigned* fb, int S, int l) {
    union { unsigned long long q[2]; s16x8 v; } u;
    const unsigned long long* p = (const unsigned long long*)(fb + (unsigned)(S * 64 + l) * 4u);
    u.q[0] = ld_coh_u64(p);
    u.q[1] = ld_coh_u64(p + 1);
    return u.v;
}

// A-fragment from 8 consecutive f32 in global memory (carry / ext paths)
__device__ __forceinline__ s16x8 frag_from_f32(const float* p) {
    float4 a = *(const float4*)p;
    float4 b = *(const float4*)(p + 4);
    union { unsigned q[4]; s16x8 v; } u;
    u.q[0] = pack2(a.x, a.y); u.q[1] = pack2(a.z, a.w);
    u.q[2] = pack2(b.x, b.y); u.q[3] = pack2(b.z, b.w);
    return u.v;
}

// ---- wave-granular cluster barrier (no syncthreads inside) ----
// Monotonic counter; each WAVE arrives independently after draining its own
// write-through stores (vmcnt 0). Target per barrier g: g*CB*WPB arrivals.
// All lanes poll gen (same address -> one coalesced L3 read per iteration).
__device__ __forceinline__ void wave_barrier(unsigned* cnt, unsigned* gen, unsigned g) {
    asm volatile("s_waitcnt vmcnt(0)" ::: "memory");
    unsigned a = 0;
    if ((threadIdx.x & 63) == 0)
        a = __hip_atomic_fetch_add(cnt, 1u, __ATOMIC_RELAXED, __HIP_MEMORY_SCOPE_AGENT);
    a = __shfl(a, 0);
    if (a == g * (CB * WPB) - 1u) {
        if ((threadIdx.x & 63) == 0)
            __hip_atomic_store(gen, g, __ATOMIC_RELAXED, __HIP_MEMORY_SCOPE_AGENT);
    } else {
        while (__hip_atomic_load(gen, __ATOMIC_RELAXED, __HIP_MEMORY_SCOPE_AGENT) < g)
            __builtin_amdgcn_s_sleep(1);
    }
}

__global__ void __launch_bounds__(256, 1)
sde_scan_kernel(const float* __restrict__ carry, const float* __restrict__ x,
                const float* __restrict__ ext,   const float* __restrict__ noise,
                const float* __restrict__ W1,    const float* __restrict__ b1,
                const float* __restrict__ W2,    const float* __restrict__ b2,
                const float* __restrict__ W3,    const float* __restrict__ b3,
                float* __restrict__ out,         void* __restrict__ ws) {
    // bf16 weight fragments. B-frag: lane = (c&15) + 16*((k>>3)&3), elem = k&7.
    __shared__ alignas(16) short W1f[2 * 5 * 64 * 8];     // 10 KB  [cg][s][lane][e]
    __shared__ alignas(16) short W2f[2 * 16 * 64 * 8];    // 32 KB
    __shared__ alignas(16) short W3fL[6 * 16 * 64 * 8];   // 96 KB  cgs 0..5 (cols 0..96)
    __shared__ alignas(16) short y_lds[4 * 64 * 8];       // 4 KB   y as A-frags [s][lane][e]
    __shared__ alignas(16) float redb[2 * 64 * 4];        // 2 KB   G2 K-split combine
    __shared__ float b1s[32], b2s[32], b3s[128];

    const int tid = threadIdx.x;
    const int bid = blockIdx.x;
    const int cl  = bid & 15;            // cluster (bid mod 16 -> same XCD under %8 rr)
    const int jb  = bid >> 4;            // block-in-cluster 0..15
    const int rb  = cl * RC;             // global batch-row base
    const int cb  = jb * 32;             // block's F1/F2 col base

    const int w  = tid >> 6;             // wave 0..3
    const int l  = tid & 63;
    const int lr = l & 15;               // frag row / output col-within-16
    const int lh = l >> 4;               // k-octet / row-quad

    unsigned* syncb = (unsigned*)ws;
    unsigned* cnt = syncb + cl * 64;
    unsigned* gen = syncb + cl * 64 + 16;
    unsigned* W3fg = (unsigned*)((char*)ws + WS_SYNC_BYTES) + cl * 8192;                       // 32 KB/cluster: cgs 6,7
    unsigned* h1f  = (unsigned*)((char*)ws + WS_SYNC_BYTES + 524288) + cl * 4096;              // 16 KB/cluster
    unsigned* h2f  = (unsigned*)((char*)ws + WS_SYNC_BYTES + 524288 + 262144) + cl * 4096;     // 16 KB/cluster

    float* yfin  = out;
    float* ys_o  = out + B_ * D_;
    float* mup_o = ys_o  + (size_t)B_ * T_ * D_;
    float* mus_o = mup_o + (size_t)B_ * T_ * D_;
    float* std_o = mus_o + (size_t)B_ * T_ * D_;

    // ---- one-time weight conversion f32 -> bf16 frags ----
    for (int e4 = tid; e4 < 160 * 8; e4 += 256) {
        int k = e4 >> 3, c0 = (e4 & 7) << 2;
        float4 v = *(const float4*)(W1 + k * F_ + cb + c0);
        float vv[4] = {v.x, v.y, v.z, v.w};
#pragma unroll
        for (int m = 0; m < 4; m++) {
            int c = c0 + m;
            W1f[((((c >> 4) * 5 + (k >> 5)) * 64) + (c & 15) + 16 * ((k >> 3) & 3)) * 8 + (k & 7)] =
                (short)f2bf(vv[m]);
        }
    }
    for (int e4 = tid; e4 < 512 * 8; e4 += 256) {
        int k = e4 >> 3, c0 = (e4 & 7) << 2;
        float4 v = *(const float4*)(W2 + k * F_ + cb + c0);
        float vv[4] = {v.x, v.y, v.z, v.w};
#pragma unroll
        for (int m = 0; m < 4; m++) {
            int c = c0 + m;
            W2f[((((c >> 4) * 16 + (k >> 5)) * 64) + (c & 15) + 16 * ((k >> 3) & 3)) * 8 + (k & 7)] =
                (short)f2bf(vv[m]);
        }
    }
    for (int cg = 0; cg < 6; cg++) {
        for (int e4 = tid; e4 < 512 * 4; e4 += 256) {
            int k = e4 >> 2, c0 = 16 * cg + ((e4 & 3) << 2);
            float4 v = *(const float4*)(W3 + (size_t)k * D_ + c0);
            float vv[4] = {v.x, v.y, v.z, v.w};
#pragma unroll
            for (int m = 0; m < 4; m++) {
                int c = c0 + m;
                W3fL[((cg * 16 + (k >> 5)) * 64 + (c & 15) + 16 * ((k >> 3) & 3)) * 8 + (k & 7)] =
                    (short)f2bf(vv[m]);
            }
        }
    }
    // W3 cgs 6,7: per-cluster global bf16 copy; block jb converts kstep s=jb.
    for (int idx = tid; idx < 512; idx += 256) {
        int cg6 = idx >> 8, lane = (idx >> 2) & 63, piece = idx & 3;
        int k = 32 * jb + 8 * (lane >> 4) + 2 * piece;
        int c = 96 + 16 * cg6 + (lane & 15);
        st_coh_u32(W3fg + ((unsigned)(cg6 * 16 + jb) * 64 + lane) * 4 + piece,
                   pack2(W3[(size_t)k * D_ + c], W3[(size_t)(k + 1) * D_ + c]));
    }
    if (tid < 32) { b1s[tid] = b1[cb + tid]; b2s[tid] = b2[cb + tid]; }
    if (tid < 128) b3s[tid] = b3[tid];
    __syncthreads();                        // LDS conversions visible block-wide
    unsigned gbar = 1;
    wave_barrier(cnt, gen, gbar);           // W3fg ready cluster-wide

    // pointwise/y state: wave w owns cols {cA, cB} x rows 4lh+i
    const int cA = 16 * w + lr;
    const int cB = 64 + 16 * w + lr;
    float y_reg[4][2];
#pragma unroll
    for (int i = 0; i < 4; i++) {
        y_reg[i][0] = carry[(size_t)(rb + 4 * lh + i) * D_ + cA];
        y_reg[i][1] = carry[(size_t)(rb + 4 * lh + i) * D_ + cB];
    }

    const f32x4 z4 = {0.f, 0.f, 0.f, 0.f};

    for (int t = 0; t < T_; t++) {
        // ============ G1 (waves 0,1): z(160) -> h1 cols [cb+16w, cb+16w+16) ============
        if (w < 2) {
            f32x4 acc = z4;
            if (t == 0) {
#pragma unroll
                for (int s = 0; s < 4; s++) {
                    s16x8 a = frag_from_f32(carry + (size_t)(rb + lr) * D_ + 32 * s + 8 * lh);
                    acc = MFMA(a, *(const s16x8*)&W1f[((w * 5 + s) * 64 + l) * 8], acc, 0, 0, 0);
                }
            } else {
#pragma unroll
                for (int s = 0; s < 4; s++) {
                    s16x8 a = *(const s16x8*)&y_lds[(s * 64 + l) * 8];
                    acc = MFMA(a, *(const s16x8*)&W1f[((w * 5 + s) * 64 + l) * 8], acc, 0, 0, 0);
                }
            }
            {
                s16x8 a = frag_from_f32(ext + ((size_t)(rb + lr) * T_ + t) * E_ + 8 * lh);
                acc = MFMA(a, *(const s16x8*)&W1f[((w * 5 + 4) * 64 + l) * 8], acc, 0, 0, 0);
            }
            const int cl_ = 16 * w + lr;
            float bb = b1s[cl_];
#pragma unroll
            for (int i = 0; i < 4; i++) {
                float v = tanhf(acc[i] + bb);
                float pv = __shfl_xor(v, 1);
                if (!(l & 1)) {
                    unsigned addr = (unsigned)(jb * 64 + 4 * lh + i + 16 * (cl_ >> 3)) * 4 + ((cl_ & 7) >> 1);
                    st_coh_u32(h1f + addr, pack2(v, pv));
                }
            }
        }
        wave_barrier(cnt, gen, ++gbar);     // h1 complete cluster-wide

        // ============ G2: h1(512) -> h2; wave = (cg2 = w>>1, khalf = w&1) ============
        {
            const int cg2 = w >> 1, kh = w & 1;
            f32x4 acc = z4;
#pragma unroll
            for (int q = 0; q < 8; q++) {
                int s = 8 * kh + q;
                s16x8 a = ld_frag(h1f, s, l);
                s16x8 b = *(const s16x8*)&W2f[((cg2 * 16 + s) * 64 + l) * 8];
                acc = MFMA(a, b, acc, 0, 0, 0);
            }
            if (kh) *(f32x4*)&redb[((w >> 1) * 64 + l) * 4] = acc;
            __syncthreads();                // S1: redb ready
            if (!kh) {
                f32x4 o = *(const f32x4*)&redb[(cg2 * 64 + l) * 4];
                const int cl_ = 16 * cg2 + lr;
                float bb = b2s[cl_];
#pragma unroll
                for (int i = 0; i < 4; i++) {
                    float v = tanhf(acc[i] + o[i] + bb);
                    float pv = __shfl_xor(v, 1);
                    if (!(l & 1)) {
                        unsigned addr = (unsigned)(jb * 64 + 4 * lh + i + 16 * (cl_ >> 3)) * 4 + ((cl_ & 7) >> 1);
                        st_coh_u32(h2f + addr, pack2(v, pv));
                    }
                }
            }
        }
        wave_barrier(cnt, gen, ++gbar);     // h2 complete cluster-wide

        // ====== G3 (all waves): h2(512) -> mu_phi for own 16 rows x cols {cA, cB} ======
        {
            // issue pointwise input loads first (latency hides under MFMA chain)
            float x1p[4][2], x2p[4][2], nvp[4][2];
#pragma unroll
            for (int i = 0; i < 4; i++) {
                size_t bt = (size_t)(rb + 4 * lh + i) * T_ + t;
                x1p[i][0] = x[bt * (2 * D_) + cA];       x1p[i][1] = x[bt * (2 * D_) + cB];
                x2p[i][0] = x[bt * (2 * D_) + D_ + cA];  x2p[i][1] = x[bt * (2 * D_) + D_ + cB];
                nvp[i][0] = noise[bt * D_ + cA];         nvp[i][1] = noise[bt * D_ + cB];
            }
            f32x4 acc0 = z4, acc1 = z4;     // acc0: col cA (cg=w), acc1: col cB (cg=4+w)
            const unsigned* bG = W3fg + (unsigned)((w >= 2 ? w - 2 : 0) * 16) * 256;
#pragma unroll
            for (int s = 0; s < 16; s++) {
                s16x8 a = ld_frag(h2f, s, l);
                s16x8 b0 = *(const s16x8*)&W3fL[((w * 16 + s) * 64 + l) * 8];
                s16x8 b1v = (w < 2) ? *(const s16x8*)&W3fL[(((4 + w) * 16 + s) * 64 + l) * 8]
                                    : ld_frag(bG, s, l);
                acc0 = MFMA(a, b0, acc0, 0, 0, 0);
                acc1 = MFMA(a, b1v, acc1, 0, 0, 0);
            }
            // pointwise + y update (y stays block-local)
#pragma unroll
            for (int i = 0; i < 4; i++) {
                int rg = rb + 4 * lh + i;
                size_t bt = (size_t)rg * T_ + t;
                {   // h = 0: col cA
                    float mu_phi = acc0[i] + b3s[cA];
                    float mu = (1.0f - ALPHA_F) * y_reg[i][0] + ALPHA_F * mu_phi + x1p[i][0];
                    float xv = x2p[i][0];
                    float sp = (xv > 0.f) ? (xv + log1pf(expf(-xv))) : log1pf(expf(xv));
                    float sd = SCALE_F * sp;
                    float yn = mu + sd * nvp[i][0];
                    mup_o[bt * D_ + cA] = mu_phi;
                    mus_o[bt * D_ + cA] = mu;
                    std_o[bt * D_ + cA] = sd;
                    ys_o [bt * D_ + cA] = yn;
                    y_reg[i][0] = yn;
                    y_lds[(((cA >> 5) * 64) + 4 * lh + i + 16 * ((cA >> 3) & 3)) * 8 + (cA & 7)] =
                        (short)f2bf(yn);
                    if (t == T_ - 1) yfin[(size_t)rg * D_ + cA] = yn;
                }
                {   // h = 1: col cB
                    float mu_phi = acc1[i] + b3s[cB];
                    float mu = (1.0f - ALPHA_F) * y_reg[i][1] + ALPHA_F * mu_phi + x1p[i][1];
                    float xv = x2p[i][1];
                    float sp = (xv > 0.f) ? (xv + log1pf(expf(-xv))) : log1pf(expf(xv));
                    float sd = SCALE_F * sp;
                    float yn = mu + sd * nvp[i][1];
                    mup_o[bt * D_ + cB] = mu_phi;
                    mus_o[bt * D_ + cB] = mu;
                    std_o[bt * D_ + cB] = sd;
                    ys_o [bt * D_ + cB] = yn;
                    y_reg[i][1] = yn;
                    y_lds[(((cB >> 5) * 64) + 4 * lh + i + 16 * ((cB >> 3) & 3)) * 8 + (cB & 7)] =
                        (short)f2bf(yn);
                    if (t == T_ - 1) yfin[(size_t)rg * D_ + cB] = yn;
                }
            }
        }
        __syncthreads();                    // S0: y_lds ready for next step's G1
    }
}

extern "C" void kernel_launch(void* const* d_in, const int* in_sizes, int n_in,
                              void* d_out, int out_size, void* d_ws, size_t ws_size,
                              hipStream_t stream) {
    const float* carry = (const float*)d_in[0];
    const float* x     = (const float*)d_in[1];
    const float* ext   = (const float*)d_in[2];
    const float* noise = (const float*)d_in[3];
    const float* W1    = (const float*)d_in[4];
    const float* b1    = (const float*)d_in[5];
    const float* W2    = (const float*)d_in[6];
    const float* b2    = (const float*)d_in[7];
    const float* W3    = (const float*)d_in[8];
    const float* b3    = (const float*)d_in[9];
    float* out = (float*)d_out;
    void* ws   = d_ws;

    // Only sync counters need zeroing (frag/weight ws buffers are written before read).
    hipMemsetAsync(d_ws, 0, WS_SYNC_BYTES, stream);

    sde_scan_kernel<<<dim3(256), dim3(256), 0, stream>>>(
        carry, x, ext, noise, W1, b1, W2, b2, W3, b3, out, ws);
}

// Round 7
// 2828.978 us; speedup vs baseline: 1.6654x; 1.6654x over previous
//
#include <hip/hip_runtime.h>
#include <cmath>

// Problem constants: B=256, T=256, D=128, E=32, F1=F2=512
#define B_   256
#define T_   256
#define D_   128
#define E_   32
#define F_   512
#define CB   16             // blocks per cluster
#define RC   16             // rows per cluster
#define NCL  16             // clusters
#define ALPHA_F 0.1f
#define SCALE_F 0.31622776601683794f   // sqrt(0.1)
#define WS_SYNC_BYTES 4096

typedef float f32x4 __attribute__((ext_vector_type(4)));
typedef short s16x8 __attribute__((ext_vector_type(8)));
#define MFMA __builtin_amdgcn_mfma_f32_16x16x32_bf16

// ---- bf16 helpers (RNE) ----
__device__ __forceinline__ unsigned short f2bf(float f) {
    unsigned u = __float_as_uint(f);
    return (unsigned short)((u + 0x7FFFu + ((u >> 16) & 1u)) >> 16);
}
__device__ __forceinline__ unsigned pack2(float lo, float hi) {
    return (unsigned)f2bf(lo) | ((unsigned)f2bf(hi) << 16);
}

// ---- coherent-point primitives (sc0 sc1) ----
__device__ __forceinline__ void st_coh_u32(unsigned* p, unsigned v) {
    __hip_atomic_store(p, v, __ATOMIC_RELAXED, __HIP_MEMORY_SCOPE_AGENT);
}
__device__ __forceinline__ unsigned long long ld_coh_u64(const unsigned long long* p) {
    return __hip_atomic_load(p, __ATOMIC_RELAXED, __HIP_MEMORY_SCOPE_AGENT);
}

// A-fragment (8 bf16) from a frag exchange buffer at the coherent point.
// Layout: u32 index (S*64 + lane)*4 + piece; lane l gets row=l&15, k=32S+8*(l>>4)+e.
__device__ __forceinline__ s16x8 ld_frag(const unsigned* fb, int S, int l) {
    union { unsigned long long q[2]; s16x8 v; } u;
    const unsigned long long* p = (const unsigned long long*)(fb + (unsigned)(S * 64 + l) * 4u);
    u.q[0] = ld_coh_u64(p);
    u.q[1] = ld_coh_u64(p + 1);
    return u.v;
}

// A-fragment from 8 consecutive f32 in global memory (carry / ext paths)
__device__ __forceinline__ s16x8 frag_from_f32(const float* p) {
    float4 a = *(const float4*)p;
    float4 b = *(const float4*)(p + 4);
    union { unsigned q[4]; s16x8 v; } u;
    u.q[0] = pack2(a.x, a.y); u.q[1] = pack2(a.z, a.w);
    u.q[2] = pack2(b.x, b.y); u.q[3] = pack2(b.z, b.w);
    return u.v;
}

// ---- cluster barrier (R5-proven shape; leaderless release via counter value) ----
// Each wave drains its write-through stores (vmcnt 0), block-syncs (so ALL waves'
// stores are drained), then thread 0 arrives on the monotonic counter and polls
// until all CB blocks of this cluster arrived for barrier g.
__device__ __forceinline__ void cluster_barrier(unsigned* gen, unsigned g) {
    asm volatile("s_waitcnt vmcnt(0)" ::: "memory");
    __syncthreads();
    if (threadIdx.x == 0) {
        __hip_atomic_fetch_add(gen, 1u, __ATOMIC_RELAXED, __HIP_MEMORY_SCOPE_AGENT);
        while (__hip_atomic_load(gen, __ATOMIC_RELAXED, __HIP_MEMORY_SCOPE_AGENT) < g * CB)
            __builtin_amdgcn_s_sleep(1);
    }
    __syncthreads();
}

__global__ void __launch_bounds__(256, 1)
sde_scan_kernel(const float* __restrict__ carry, const float* __restrict__ x,
                const float* __restrict__ ext,   const float* __restrict__ noise,
                const float* __restrict__ W1,    const float* __restrict__ b1,
                const float* __restrict__ W2,    const float* __restrict__ b2,
                const float* __restrict__ W3,    const float* __restrict__ b3,
                float* __restrict__ out,         void* __restrict__ ws) {
    // W3 bf16 frags [cg(8)][s(16)][lane][e] = 128 KB; first 42 KB reused at init
    // to stage W1/W2 frags before they move to registers.
    __shared__ alignas(16) short W3f[8 * 16 * 64 * 8];   // 131072 B
    __shared__ alignas(16) short y_lds[4 * 64 * 8];      // 4096 B   y as A-frags [s][lane][e]
    __shared__ alignas(16) float redb[24 * 64 * 4];      // 24576 B  partial-tile exchange
    __shared__ float b1s[32], b2s[32], b3s[128];

    const int tid = threadIdx.x;
    const int bid = blockIdx.x;
    const int cl  = bid & 15;            // cluster (bid%16 -> same XCD pair under rr)
    const int jb  = bid >> 4;            // block-in-cluster 0..15
    const int rb  = cl * RC;             // global batch-row base
    const int cb  = jb * 32;             // block's F1/F2 col base

    const int w  = tid >> 6;             // wave 0..3
    const int l  = tid & 63;
    const int lr = l & 15;               // frag row / col-within-16
    const int lh = l >> 4;               // k-octet / row-quad

    unsigned* gen = (unsigned*)ws + cl * 64;   // 256B stride per cluster
    unsigned* h1f = (unsigned*)((char*)ws + WS_SYNC_BYTES) + cl * 4096;            // 16 KB/cluster
    unsigned* h2f = (unsigned*)((char*)ws + WS_SYNC_BYTES + 262144) + cl * 4096;   // 16 KB/cluster

    float* yfin  = out;
    float* ys_o  = out + B_ * D_;
    float* mup_o = ys_o  + (size_t)B_ * T_ * D_;
    float* mus_o = mup_o + (size_t)B_ * T_ * D_;
    float* std_o = mus_o + (size_t)B_ * T_ * D_;

    // ================= init: stage W1/W2 frags in LDS, move to registers =================
    short* stg1 = W3f;            // W1 frags [cg(2)][s(5)][lane][e]  (5120 shorts)
    short* stg2 = W3f + 5120;     // W2 frags [cg(2)][s(16)][lane][e] (16384 shorts)
    for (int e4 = tid; e4 < 160 * 8; e4 += 256) {
        int k = e4 >> 3, c0 = (e4 & 7) << 2;
        float4 v = *(const float4*)(W1 + k * F_ + cb + c0);
        float vv[4] = {v.x, v.y, v.z, v.w};
#pragma unroll
        for (int m = 0; m < 4; m++) {
            int c = c0 + m;
            stg1[((((c >> 4) * 5 + (k >> 5)) * 64) + (c & 15) + 16 * ((k >> 3) & 3)) * 8 + (k & 7)] =
                (short)f2bf(vv[m]);
        }
    }
    for (int e4 = tid; e4 < 512 * 8; e4 += 256) {
        int k = e4 >> 3, c0 = (e4 & 7) << 2;
        float4 v = *(const float4*)(W2 + k * F_ + cb + c0);
        float vv[4] = {v.x, v.y, v.z, v.w};
#pragma unroll
        for (int m = 0; m < 4; m++) {
            int c = c0 + m;
            stg2[((((c >> 4) * 16 + (k >> 5)) * 64) + (c & 15) + 16 * ((k >> 3) & 3)) * 8 + (k & 7)] =
                (short)f2bf(vv[m]);
        }
    }
    if (tid < 32) { b1s[tid] = b1[cb + tid]; b2s[tid] = b2[cb + tid]; }
    if (tid < 128) b3s[tid] = b3[tid];
    __syncthreads();

    s16x8 w1r[5];                 // G1 B-frags (valid for waves 0,1)
    {
        int wg = (w < 2) ? w : 0;
#pragma unroll
        for (int s = 0; s < 5; s++) w1r[s] = *(const s16x8*)&stg1[((wg * 5 + s) * 64 + l) * 8];
    }
    s16x8 w2r0[4], w2r1[4];       // G2 B-frags: cg0/cg1 for s = 4w..4w+3
#pragma unroll
    for (int q = 0; q < 4; q++) {
        w2r0[q] = *(const s16x8*)&stg2[((0 * 16 + 4 * w + q) * 64 + l) * 8];
        w2r1[q] = *(const s16x8*)&stg2[((1 * 16 + 4 * w + q) * 64 + l) * 8];
    }
    __syncthreads();

    // W3 -> LDS frags (full 128 cols, overwrites staging)
    for (int cg = 0; cg < 8; cg++) {
        for (int e4 = tid; e4 < 512 * 4; e4 += 256) {
            int k = e4 >> 2, c0 = 16 * cg + ((e4 & 3) << 2);
            float4 v = *(const float4*)(W3 + (size_t)k * D_ + c0);
            float vv[4] = {v.x, v.y, v.z, v.w};
#pragma unroll
            for (int m = 0; m < 4; m++) {
                int c = c0 + m;
                W3f[((cg * 16 + (k >> 5)) * 64 + (c & 15) + 16 * ((k >> 3) & 3)) * 8 + (k & 7)] =
                    (short)f2bf(vv[m]);
            }
        }
    }
    __syncthreads();

    // pointwise/y state: wave w owns cols {32w+lr, 32w+16+lr} x rows 4lh+i
    const int cA = 32 * w + lr;
    const int cB = 32 * w + 16 + lr;
    float y_reg[4][2];
#pragma unroll
    for (int i = 0; i < 4; i++) {
        y_reg[i][0] = carry[(size_t)(rb + 4 * lh + i) * D_ + cA];
        y_reg[i][1] = carry[(size_t)(rb + 4 * lh + i) * D_ + cB];
    }

    const f32x4 z4 = {0.f, 0.f, 0.f, 0.f};
    unsigned gbar = 0;

    for (int t = 0; t < T_; t++) {
        // ---- prefetch pointwise inputs (consumed in G3; hides under both barriers) ----
        float x1p[4][2], x2p[4][2], nvp[4][2];
#pragma unroll
        for (int i = 0; i < 4; i++) {
            size_t bt = (size_t)(rb + 4 * lh + i) * T_ + t;
            x1p[i][0] = x[bt * (2 * D_) + cA];       x1p[i][1] = x[bt * (2 * D_) + cB];
            x2p[i][0] = x[bt * (2 * D_) + D_ + cA];  x2p[i][1] = x[bt * (2 * D_) + D_ + cB];
            nvp[i][0] = noise[bt * D_ + cA];         nvp[i][1] = noise[bt * D_ + cB];
        }

        // ============ G1 (waves 0,1): z(160) -> h1 cols [cb+16w, cb+16w+16) ============
        if (w < 2) {
            f32x4 acc = z4;
            if (t == 0) {
#pragma unroll
                for (int s = 0; s < 4; s++) {
                    s16x8 a = frag_from_f32(carry + (size_t)(rb + lr) * D_ + 32 * s + 8 * lh);
                    acc = MFMA(a, w1r[s], acc, 0, 0, 0);
                }
            } else {
#pragma unroll
                for (int s = 0; s < 4; s++) {
                    s16x8 a = *(const s16x8*)&y_lds[(s * 64 + l) * 8];
                    acc = MFMA(a, w1r[s], acc, 0, 0, 0);
                }
            }
            {
                s16x8 a = frag_from_f32(ext + ((size_t)(rb + lr) * T_ + t) * E_ + 8 * lh);
                acc = MFMA(a, w1r[4], acc, 0, 0, 0);
            }
            const int cl_ = 16 * w + lr;
            float bb = b1s[cl_];
#pragma unroll
            for (int i = 0; i < 4; i++) {
                float v = tanhf(acc[i] + bb);
                float pv = __shfl_xor(v, 1);
                if (!(l & 1)) {
                    unsigned addr = (unsigned)(jb * 64 + 4 * lh + i + 16 * (cl_ >> 3)) * 4 + ((cl_ & 7) >> 1);
                    st_coh_u32(h1f + addr, pack2(v, pv));
                }
            }
        }
        cluster_barrier(gen, ++gbar);       // h1 complete cluster-wide

        // ============ G2 (all waves): h1(512) -> h2 cols [cb..cb+32); K-split 4 ways ============
        {
            s16x8 a4[4];
#pragma unroll
            for (int q = 0; q < 4; q++) a4[q] = ld_frag(h1f, 4 * w + q, l);
            f32x4 acc0 = z4, acc1 = z4;
#pragma unroll
            for (int q = 0; q < 4; q++) {
                acc0 = MFMA(a4[q], w2r0[q], acc0, 0, 0, 0);
                acc1 = MFMA(a4[q], w2r1[q], acc1, 0, 0, 0);
            }
            // partial exchange: cg0 partials from w1,w2,w3 -> slots 0,1,2; cg1 from w0,w2,w3 -> 3,4,5
            if (w == 0) { *(f32x4*)&redb[((3) * 64 + l) * 4] = acc1; }
            else if (w == 1) { *(f32x4*)&redb[((0) * 64 + l) * 4] = acc0; }
            else if (w == 2) { *(f32x4*)&redb[((1) * 64 + l) * 4] = acc0; *(f32x4*)&redb[((4) * 64 + l) * 4] = acc1; }
            else             { *(f32x4*)&redb[((2) * 64 + l) * 4] = acc0; *(f32x4*)&redb[((5) * 64 + l) * 4] = acc1; }
            __syncthreads();
            if (w < 2) {
                f32x4 s = (w == 0) ? acc0 : acc1;
                int base = (w == 0) ? 0 : 3;
#pragma unroll
                for (int m = 0; m < 3; m++) s += *(const f32x4*)&redb[((base + m) * 64 + l) * 4];
                const int cl_ = 16 * w + lr;
                float bb = b2s[cl_];
#pragma unroll
                for (int i = 0; i < 4; i++) {
                    float v = tanhf(s[i] + bb);
                    float pv = __shfl_xor(v, 1);
                    if (!(l & 1)) {
                        unsigned addr = (unsigned)(jb * 64 + 4 * lh + i + 16 * (cl_ >> 3)) * 4 + ((cl_ & 7) >> 1);
                        st_coh_u32(h2f + addr, pack2(v, pv));
                    }
                }
            }
        }
        cluster_barrier(gen, ++gbar);       // h2 complete cluster-wide

        // ====== G3 (all waves): h2(512) -> mu_phi, all 128 cols; K-split 4 ways ======
        {
            s16x8 a4[4];
#pragma unroll
            for (int q = 0; q < 4; q++) a4[q] = ld_frag(h2f, 4 * w + q, l);
            f32x4 accT[8];
#pragma unroll
            for (int T = 0; T < 8; T++) accT[T] = z4;
#pragma unroll
            for (int q = 0; q < 4; q++) {
#pragma unroll
                for (int T = 0; T < 8; T++) {
                    s16x8 b = *(const s16x8*)&W3f[((T * 16 + 4 * w + q) * 64 + l) * 8];
                    accT[T] = MFMA(a4[q], b, accT[T], 0, 0, 0);
                }
            }
            // extract own tiles (static reg indexing), stash others in redb
            f32x4 own0 = z4, own1 = z4;
#pragma unroll
            for (int T = 0; T < 8; T++) {
                if (T == 2 * w)     own0 = accT[T];
                if (T == 2 * w + 1) own1 = accT[T];
                if ((T >> 1) != w) {
                    int pos = T - ((T >= 2 * w + 2) ? 2 : 0);
                    *(f32x4*)&redb[((w * 6 + pos) * 64 + l) * 4] = accT[T];
                }
            }
            __syncthreads();
            // combine own tiles + pointwise epilogue
#pragma unroll
            for (int j = 0; j < 2; j++) {
                const int T = 2 * w + j;
                f32x4 s = j ? own1 : own0;
#pragma unroll
                for (int wp = 0; wp < 4; wp++) {
                    if (wp != w) {
                        int pos = T - ((T >= 2 * wp + 2) ? 2 : 0);
                        s += *(const f32x4*)&redb[((wp * 6 + pos) * 64 + l) * 4];
                    }
                }
                const int c = 32 * w + 16 * j + lr;
                float bb = b3s[c];
#pragma unroll
                for (int i = 0; i < 4; i++) {
                    float mu_phi = s[i] + bb;
                    int rg = rb + 4 * lh + i;
                    size_t bt = (size_t)rg * T_ + t;
                    float mu = (1.0f - ALPHA_F) * y_reg[i][j] + ALPHA_F * mu_phi + x1p[i][j];
                    float xv = x2p[i][j];
                    float sp = (xv > 0.f) ? (xv + log1pf(expf(-xv))) : log1pf(expf(xv));
                    float sd = SCALE_F * sp;
                    float yn = mu + sd * nvp[i][j];
                    mup_o[bt * D_ + c] = mu_phi;
                    mus_o[bt * D_ + c] = mu;
                    std_o[bt * D_ + c] = sd;
                    ys_o [bt * D_ + c] = yn;
                    y_reg[i][j] = yn;
                    y_lds[(((c >> 5) * 64) + 4 * lh + i + 16 * ((c >> 3) & 3)) * 8 + (c & 7)] =
                        (short)f2bf(yn);
                    if (t == T_ - 1) yfin[(size_t)rg * D_ + c] = yn;
                }
            }
        }
        __syncthreads();                    // y_lds ready for next step's G1
    }
}

extern "C" void kernel_launch(void* const* d_in, const int* in_sizes, int n_in,
                              void* d_out, int out_size, void* d_ws, size_t ws_size,
                              hipStream_t stream) {
    const float* carry = (const float*)d_in[0];
    const float* x     = (const float*)d_in[1];
    const float* ext   = (const float*)d_in[2];
    const float* noise = (const float*)d_in[3];
    const float* W1    = (const float*)d_in[4];
    const float* b1    = (const float*)d_in[5];
    const float* W2    = (const float*)d_in[6];
    const float* b2    = (const float*)d_in[7];
    const float* W3    = (const float*)d_in[8];
    const float* b3    = (const float*)d_in[9];
    float* out = (float*)d_out;
    void* ws   = d_ws;

    // Only sync counters need zeroing (frag buffers are written before read each step).
    hipMemsetAsync(d_ws, 0, WS_SYNC_BYTES, stream);

    sde_scan_kernel<<<dim3(256), dim3(256), 0, stream>>>(
        carry, x, ext, noise, W1, b1, W2, b2, W3, b3, out, ws);
}